// Round 1
// 150.147 us; speedup vs baseline: 1.0220x; 1.0220x over previous
//
#include <hip/hip_runtime.h>
#include <hip/hip_bf16.h>

// MultiHeadAttention: B=4, T=2048, D=512, H=8, K=64.
// Inputs fp32, output fp32, intermediates bf16.
// [0] cvt {x, w_qkv} -> bf16
// [1] gemm_bb: qk = x@w_qkv^T (q pre-scaled); v written TRANSPOSED + s-PERMUTED to vT
// [2] attn_v7: flash attn; swapped QK^T (S^T) so P stays in-register; V s-order
//     pre-permuted so pk2-packed P feeds PV directly. K/V double-buffered,
//     1 barrier/tile. No P LDS round-trip.
// [3] gemm_b64: out = attn @ w_proj^T + b_proj
//
// R15 (attn v7): v6 spent 16 ds_write_u16 + 2 ds_read_b128 + 2 barriers/tile
// on the P C->A relayout. Operand-swapped QK^T puts q on lane15; MFMA k-sum is
// permutation-invariant, so permuting V's s-order (within 32-chunks) at the
// gemm1 write makes the packed P registers a valid A-fragment as-is.
// ws: qk 16 MiB + vT 8 MiB + xb 8 MiB = 32 MiB.

typedef unsigned short u16;
typedef __attribute__((ext_vector_type(8))) __bf16 bf16x8;
typedef __attribute__((ext_vector_type(8))) unsigned short u16x8;
typedef __attribute__((ext_vector_type(4))) unsigned short u16x4;
typedef __attribute__((ext_vector_type(4))) float f32x4;
typedef __attribute__((ext_vector_type(4))) unsigned u32x4;
typedef __attribute__((ext_vector_type(2))) unsigned u32x2;

#define DEV static __device__ __forceinline__

DEV void async16(const u16* g, u16* l) {  // global->LDS DMA, 16B/lane
  __builtin_amdgcn_global_load_lds(
      (const __attribute__((address_space(1))) unsigned int*)g,
      (__attribute__((address_space(3))) unsigned int*)l, 16, 0, 0);
}
DEV u16x8 gld8(const u16* p) { return *(const u16x8*)p; }
DEV void lst8(u16* p, u16x8 v) { *(u16x8*)p = v; }
DEV bf16x8 ldsld8(const u16* p) {
  return __builtin_bit_cast(bf16x8, *(const u16x8*)p);
}
DEV f32x4 mfma16(bf16x8 a, bf16x8 b, f32x4 c) {
  return __builtin_amdgcn_mfma_f32_16x16x32_bf16(a, b, c, 0, 0, 0);
}
DEV u16 f2b(float f) {  // fp32 -> bf16 RNE (epilogue-only)
  unsigned u = __builtin_bit_cast(unsigned, f);
  u += 0x7FFFu + ((u >> 16) & 1u);
  return (u16)(u >> 16);
}
DEV unsigned pk2(float x, float y) {  // v_cvt_pk_bf16_f32: low=x, high=y
  __hip_bfloat162 t = __float22bfloat162_rn(float2{x, y});
  unsigned r;
  __builtin_memcpy(&r, &t, 4);
  return r;
}
DEV u16x8 pack8(f32x4 a, f32x4 b) {
  u32x4 t;
  t[0] = pk2(a[0], a[1]);
  t[1] = pk2(a[2], a[3]);
  t[2] = pk2(b[0], b[1]);
  t[3] = pk2(b[2], b[3]);
  return __builtin_bit_cast(u16x8, t);
}

// ---------------------------------------------------------------------------
// fp32 -> bf16: x (8192x512) -> xb, w_qkv (1536x512) -> wqb (parked in d_out)
__global__ void cvt_all(const float* __restrict__ x, const float* __restrict__ wq,
                        u16* __restrict__ xb, u16* __restrict__ wqb) {
  constexpr long NX = 8192L * 512 / 8;
  constexpr long NQ = 1536L * 512 / 8;
  const long i = (long)blockIdx.x * 256 + threadIdx.x;
  if (i < NX) {
    const float* p = x + i * 8;
    *(u16x8*)(xb + i * 8) = pack8(*(const f32x4*)p, *(const f32x4*)(p + 4));
  } else if (i < NX + NQ) {
    const long j = i - NX;
    const float* p = wq + j * 8;
    *(u16x8*)(wqb + j * 8) = pack8(*(const f32x4*)p, *(const f32x4*)(p + 4));
  }
}

// ---------------------------------------------------------------------------
// gemm1: qkv projection. A[M,512](bf16) @ Bt[1536,512](bf16)^T.
// BM=BN=128, BK=64; both operands async16; XCD-swizzled grid (rt shares i%8).
// Output routing (block-uniform on col0):
//   cols <1024  -> qk[row*1024 + col], q cols (<512) scaled by 0.125*log2e
//   cols >=1024 -> vT[b][col-1024][perm(s)] (V transposed; s-order permuted
//                  within each 32-chunk: pos = qd*8 + a*4 + r for
//                  s = a*16 + qd*4 + r — matches attn_v7's in-register P k-order)
// ---------------------------------------------------------------------------
__global__ void gemm_bb(const u16* __restrict__ A, const u16* __restrict__ Bt,
                        u16* __restrict__ qk, u16* __restrict__ vT, int K) {
  __shared__ __align__(16) u16 As[2][128 * 32];
  __shared__ __align__(16) u16 Bs[2][128 * 32];

  const int t = threadIdx.x, lane = t & 63, w = t >> 6;
  const int lane15 = lane & 15, quad = lane >> 4;
  const int wr = w >> 1, wc = w & 1;

  const int i = blockIdx.x;
  const int rt = (i & 7) | (((i >> 3) & 7) << 3);  // 0..63
  const int ct = i >> 6;                           // 0..11
  const long row0 = (long)rt * 128;
  const int col0 = ct * 128;

  const int srow = w * 16 + (lane >> 2);
  const int scol = (lane & 3) * 8;
  const u16* Ag = A + (row0 + srow) * (long)K + scol;
  const u16* Bg = Bt + ((long)col0 + srow) * (long)K + scol;

  f32x4 acc[4][4];
#pragma unroll
  for (int ii = 0; ii < 4; ii++)
#pragma unroll
    for (int j = 0; j < 4; j++) acc[ii][j] = (f32x4)(0.0f);

  for (int k0 = 0; k0 < K; k0 += 64) {
    __syncthreads();
#pragma unroll
    for (int r = 0; r < 2; r++)
#pragma unroll
      for (int hf = 0; hf < 2; hf++) {
        async16(Ag + (long)r * 64 * K + k0 + hf * 32,
                &As[hf][(r * 64 + w * 16) * 32]);
        async16(Bg + (long)r * 64 * K + k0 + hf * 32,
                &Bs[hf][(r * 64 + w * 16) * 32]);
      }
    __syncthreads();

#pragma unroll
    for (int hf = 0; hf < 2; hf++) {
      bf16x8 a[4], b[4];
#pragma unroll
      for (int ii = 0; ii < 4; ii++)
        a[ii] = ldsld8(&As[hf][(wr * 64 + ii * 16 + lane15) * 32 + quad * 8]);
#pragma unroll
      for (int j = 0; j < 4; j++)
        b[j] = ldsld8(&Bs[hf][(wc * 64 + j * 16 + lane15) * 32 + quad * 8]);
#pragma unroll
      for (int ii = 0; ii < 4; ii++)
#pragma unroll
        for (int j = 0; j < 4; j++) acc[ii][j] = mfma16(a[ii], b[j], acc[ii][j]);
    }
  }

  if (col0 >= 1024) {
    // V part -> transposed + s-permuted: vT[(b*512 + hd)*2048 + perm(s)]
#pragma unroll
    for (int ii = 0; ii < 4; ii++)
#pragma unroll
      for (int j = 0; j < 4; j++) {
        const int hd = col0 - 1024 + wc * 64 + j * 16 + lane15;
        const long row = row0 + wr * 64 + ii * 16 + quad * 4;
        const long bb = row >> 11;
        const int s = (int)(row & 2047);  // s & 3 == 0
        const int ps = (s & ~31) | (((s >> 2) & 3) << 3) | (((s >> 4) & 1) << 2);
        u32x2 pr;
        pr[0] = pk2(acc[ii][j][0], acc[ii][j][1]);
        pr[1] = pk2(acc[ii][j][2], acc[ii][j][3]);
        *(u16x4*)(vT + (bb * 512 + hd) * 2048 + ps) =
            __builtin_bit_cast(u16x4, pr);
      }
  } else {
    // Q/K part -> qk (LD=1024); q cols pre-scaled for attn's exp2
#pragma unroll
    for (int ii = 0; ii < 4; ii++)
#pragma unroll
      for (int j = 0; j < 4; j++) {
        const int col = col0 + wc * 64 + j * 16 + lane15;
        const float sc = (col < 512) ? 0.18033688f : 1.0f;
#pragma unroll
        for (int r = 0; r < 4; r++) {
          const long row = row0 + wr * 64 + ii * 16 + quad * 4 + r;
          qk[row * 1024 + col] = f2b(acc[ii][j][r] * sc);
        }
      }
  }
}

// ---------------------------------------------------------------------------
// gemm3: C[M,512](fp32) = A[M,512](bf16) @ Bt[512,512](fp32)^T + bias.
// BM=128, BN=64, BK=64; XCD-swizzled. (R8/R13-proven)
// ---------------------------------------------------------------------------
__global__ void gemm_b64(const u16* __restrict__ A, const float* __restrict__ Bt,
                         const float* __restrict__ bias, float* __restrict__ C,
                         int N, int K) {
  __shared__ __align__(16) u16 As[2][128 * 32];
  __shared__ __align__(16) u16 Bs[2][64 * 32];

  const int t = threadIdx.x, lane = t & 63, w = t >> 6;
  const int lane15 = lane & 15, quad = lane >> 4;
  const int wr = w >> 1, wc = w & 1;

  const int i = blockIdx.x;
  const int rt = (i & 7) | (((i >> 3) & 7) << 3);
  const int ct = i >> 6;
  const long row0 = (long)rt * 128;
  const int col0 = ct * 64;

  const int srow = w * 16 + (lane >> 2);
  const int scol = (lane & 3) * 8;
  const u16* Ag = A + (row0 + srow) * (long)K + scol;

  const int brow = t >> 2, bc = (t & 3) * 16;
  const float* Bg = Bt + (long)(col0 + brow) * K + bc;
  u16* BsD = &Bs[bc >> 5][brow * 32 + (bc & 31)];

  f32x4 acc[4][2];
#pragma unroll
  for (int ii = 0; ii < 4; ii++)
#pragma unroll
    for (int j = 0; j < 2; j++) acc[ii][j] = (f32x4)(0.0f);

  f32x4 q0 = *(const f32x4*)Bg, q1 = *(const f32x4*)(Bg + 4);
  f32x4 q2 = *(const f32x4*)(Bg + 8), q3 = *(const f32x4*)(Bg + 12);

  for (int k0 = 0; k0 < K; k0 += 64) {
    __syncthreads();
#pragma unroll
    for (int r = 0; r < 2; r++)
#pragma unroll
      for (int hf = 0; hf < 2; hf++)
        async16(Ag + (long)r * 64 * K + k0 + hf * 32,
                &As[hf][(r * 64 + w * 16) * 32]);
    lst8(BsD, pack8(q0, q1));
    lst8(BsD + 8, pack8(q2, q3));
    __syncthreads();

    {
      const int kp = (k0 + 64 < K) ? k0 + 64 : k0;
      q0 = *(const f32x4*)(Bg + kp);     q1 = *(const f32x4*)(Bg + kp + 4);
      q2 = *(const f32x4*)(Bg + kp + 8); q3 = *(const f32x4*)(Bg + kp + 12);
    }

#pragma unroll
    for (int hf = 0; hf < 2; hf++) {
      bf16x8 a[4], b[2];
#pragma unroll
      for (int ii = 0; ii < 4; ii++)
        a[ii] = ldsld8(&As[hf][(wr * 64 + ii * 16 + lane15) * 32 + quad * 8]);
#pragma unroll
      for (int j = 0; j < 2; j++)
        b[j] = ldsld8(&Bs[hf][(wc * 32 + j * 16 + lane15) * 32 + quad * 8]);
#pragma unroll
      for (int ii = 0; ii < 4; ii++)
#pragma unroll
        for (int j = 0; j < 2; j++) acc[ii][j] = mfma16(a[ii], b[j], acc[ii][j]);
    }
  }

#pragma unroll
  for (int ii = 0; ii < 4; ii++)
#pragma unroll
    for (int j = 0; j < 2; j++) {
      const int col = col0 + wc * 32 + j * 16 + lane15;
      const float bv = bias[col];
#pragma unroll
      for (int r = 0; r < 4; r++) {
        const long row = row0 + wr * 64 + ii * 16 + quad * 4 + r;
        C[row * (long)N + col] = acc[ii][j][r] + bv;
      }
    }
}

// ---------------------------------------------------------------------------
// attn_v7: swapped-operand QK^T (S^T = K@Q) so each lane holds a full 64-s
// P strip for q=lane15. pk2-packed registers ARE the PV A-fragment because
// vT was written with the matching within-32 s-permutation (MFMA k-sum is
// permutation invariant when A and B use the same k-order). K/V double-
// buffered in LDS -> 1 barrier per tile. No Ps buffer, no in-tile shuffles.
// 1024 blocks, 256 threads.
// ---------------------------------------------------------------------------
__global__ void attn_v7(const u16* __restrict__ qk, const u16* __restrict__ vT,
                        u16* __restrict__ out) {
  constexpr int T = 2048, LDQ = 1024;
  __shared__ __align__(16) u16 Ks[2][64 * 72];
  __shared__ __align__(16) u16 Vs[2][64 * 72];  // V^T rows (s pre-permuted)

  const int t = threadIdx.x, lane = t & 63, w = t >> 6;
  const int lane15 = lane & 15, quad = lane >> 4;

  const int i = blockIdx.x;
  int qb = i & 31;
  if (i >= 512) qb = 31 - qb;  // load-balance
  const int h = (i >> 5) & 7;
  const int b = (i >> 8) & 3;
  const long baseq = (long)b * T * LDQ;
  const u16* vTb = vT + ((long)b * 512 + h * 64) * 2048;  // rows d, stride 2048

  const u16* gq =
      qk + baseq + (long)(qb * 64 + w * 16 + lane15) * LDQ + h * 64 + quad * 8;
  const bf16x8 qa0 = __builtin_bit_cast(bf16x8, *(const u16x8*)gq);
  const bf16x8 qa1 = __builtin_bit_cast(bf16x8, *(const u16x8*)(gq + 32));

  const int srow = t >> 3, sc8 = (t & 7) * 8;  // rows {srow, srow+32}
  const int nsb = qb + 1;

  u16x8 kr0, kr1, vr0, vr1;
  {  // tile 0 -> regs
    const u16* gk = qk + baseq + (long)srow * LDQ + 512 + h * 64 + sc8;
    kr0 = gld8(gk); kr1 = gld8(gk + (long)32 * LDQ);
    const u16* gv = vTb + (long)srow * 2048 + sc8;
    vr0 = gld8(gv); vr1 = gld8(gv + (long)32 * 2048);
  }
  lst8(&Ks[0][srow * 72 + sc8], kr0);
  lst8(&Ks[0][(srow + 32) * 72 + sc8], kr1);
  lst8(&Vs[0][srow * 72 + sc8], vr0);
  lst8(&Vs[0][(srow + 32) * 72 + sc8], vr1);
  {  // tile 1 -> regs (clamped)
    const int sp = (nsb > 1) ? 1 : 0;
    const u16* gk =
        qk + baseq + (long)(sp * 64 + srow) * LDQ + 512 + h * 64 + sc8;
    kr0 = gld8(gk); kr1 = gld8(gk + (long)32 * LDQ);
    const u16* gv = vTb + (long)srow * 2048 + sp * 64 + sc8;
    vr0 = gld8(gv); vr1 = gld8(gv + (long)32 * 2048);
  }

  float lpl = 0.0f;  // per-lane row-sum for q = lane15
  f32x4 o[4];
#pragma unroll
  for (int j = 0; j < 4; j++) o[j] = (f32x4)(0.0f);

  const int qin = w * 16 + lane15;  // q within the 64-row block

  for (int sb = 0; sb < nsb; ++sb) {
    const u16* Kc = Ks[sb & 1];
    const u16* Vc = Vs[sb & 1];
    u16* Kn = Ks[(sb + 1) & 1];
    u16* Vn = Vs[(sb + 1) & 1];

    __syncthreads();  // buf[sb&1] writes visible; buf[(sb+1)&1] readers done

    // stage tile sb+1 into the other buffer (no barrier needed before compute)
    lst8(&Kn[srow * 72 + sc8], kr0);
    lst8(&Kn[(srow + 32) * 72 + sc8], kr1);
    lst8(&Vn[srow * 72 + sc8], vr0);
    lst8(&Vn[(srow + 32) * 72 + sc8], vr1);

    {  // prefetch tile sb+2 (clamped) into regs
      const int sp = (sb + 2 < nsb) ? sb + 2 : nsb - 1;
      const u16* gk =
          qk + baseq + (long)(sp * 64 + srow) * LDQ + 512 + h * 64 + sc8;
      kr0 = gld8(gk); kr1 = gld8(gk + (long)32 * LDQ);
      const u16* gv = vTb + (long)srow * 2048 + sp * 64 + sc8;
      vr0 = gld8(gv); vr1 = gld8(gv + (long)32 * 2048);
    }

    // S^T strip (64 s x 16 q): A=K (rows s), B=q -> lane holds q=lane15,
    // s = 16j + 4*quad + r
    f32x4 sf[4];
#pragma unroll
    for (int j = 0; j < 4; j++) {
      f32x4 z = (f32x4)(0.0f);
      z = mfma16(ldsld8(&Kc[(j * 16 + lane15) * 72 + quad * 8]), qa0, z);
      sf[j] = mfma16(ldsld8(&Kc[(j * 16 + lane15) * 72 + quad * 8 + 32]), qa1, z);
    }

    // p = exp2(s); causal zeroing on diag block only
    if (sb == qb) {
#pragma unroll
      for (int j = 0; j < 4; j++)
#pragma unroll
        for (int r = 0; r < 4; r++) {
          float p = exp2f(sf[j][r]);
          if (j * 16 + quad * 4 + r > qin) p = 0.0f;
          sf[j][r] = p;
          lpl += p;
        }
    } else {
#pragma unroll
      for (int j = 0; j < 4; j++)
#pragma unroll
        for (int r = 0; r < 4; r++) {
          const float p = exp2f(sf[j][r]);
          sf[j][r] = p;
          lpl += p;
        }
    }

    // pack P -> A-fragments in-register; k-order = (j, r) per quad, which is
    // exactly vT's permuted s-order. No LDS, no shuffles.
    u32x4 pw0, pw1;
    pw0[0] = pk2(sf[0][0], sf[0][1]); pw0[1] = pk2(sf[0][2], sf[0][3]);
    pw0[2] = pk2(sf[1][0], sf[1][1]); pw0[3] = pk2(sf[1][2], sf[1][3]);
    pw1[0] = pk2(sf[2][0], sf[2][1]); pw1[1] = pk2(sf[2][2], sf[2][3]);
    pw1[2] = pk2(sf[3][0], sf[3][1]); pw1[3] = pk2(sf[3][2], sf[3][3]);
    const bf16x8 pa0 = __builtin_bit_cast(bf16x8, pw0);
    const bf16x8 pa1 = __builtin_bit_cast(bf16x8, pw1);

    // O += P @ V from Vc (V^T rows, permuted s): plain b128 reads
#pragma unroll
    for (int j = 0; j < 4; j++) {
      const int d0 = (j * 16 + lane15) * 72;
      o[j] = mfma16(pa0, ldsld8(&Vc[d0 + quad * 8]), o[j]);
      o[j] = mfma16(pa1, ldsld8(&Vc[d0 + quad * 8 + 32]), o[j]);
    }
  }

  // row-sum reduce: lanes {q, q+16, q+32, q+48} hold partials for q=lane15
  lpl += __shfl_xor(lpl, 16);
  lpl += __shfl_xor(lpl, 32);

  const long orow0 = (long)b * T + qb * 64 + w * 16;
  float inv[4];
#pragma unroll
  for (int r = 0; r < 4; r++) inv[r] = 1.0f / __shfl(lpl, quad * 4 + r);
#pragma unroll
  for (int j = 0; j < 4; j++)
#pragma unroll
    for (int r = 0; r < 4; r++)
      out[(orow0 + quad * 4 + r) * 512 + h * 64 + j * 16 + lane15] =
          f2b(o[j][r] * inv[r]);
}

// ---------------------------------------------------------------------------
extern "C" void kernel_launch(void* const* d_in, const int* in_sizes, int n_in,
                              void* d_out, int out_size, void* d_ws, size_t ws_size,
                              hipStream_t stream) {
  const float* x      = (const float*)d_in[0];  // [4,2048,512] fp32
  const float* w_qkv  = (const float*)d_in[1];  // [1536,512]  fp32
  const float* w_proj = (const float*)d_in[2];  // [512,512]   fp32
  const float* b_proj = (const float*)d_in[3];  // [512]       fp32
  float* out = (float*)d_out;                   // [4,2048,512] fp32

  u16* qk = (u16*)d_ws;                   // [8192 x 1024] bf16 = 16 MiB
  u16* vT = qk + (size_t)8192 * 1024;     // [4 x 512 x 2048] bf16 = 8 MiB
  u16* xb = vT + (size_t)4 * 512 * 2048;  // [8192 x 512] bf16 = 8 MiB
                                          // (x_bf16, then attn output)
  u16* wqb = (u16*)d_out;                 // w_qkv bf16 parked in d_out

  // [0] convert x and w_qkv to bf16
  cvt_all<<<2432, 256, 0, stream>>>(x, w_qkv, xb, wqb);
  // [1] qkv projection: qk + transposed/permuted vT
  gemm_bb<<<768, 256, 0, stream>>>(xb, wqb, qk, vT, 512);
  // [2] causal flash attention (overwrites xb)
  attn_v7<<<1024, 256, 0, stream>>>(qk, vT, xb);
  // [3] output projection + bias -> fp32 d_out
  gemm_b64<<<512, 256, 0, stream>>>(xb, w_proj, b_proj, out, 512, 512);
}